// Round 14
// baseline (35.751 us; speedup 1.0000x reference)
//
#include <hip/hip_runtime.h>
#include <hip/hip_fp16.h>
#include <math.h>

#define D_DET 512
#define N_ANG 180
#define S_IMG 512
#define NPIX  (S_IMG * S_IMG)
#define T_MAX 63                 // ramp tap truncation

typedef _Float16 half2v __attribute__((ext_vector_type(2)));

__device__ __constant__ float kPI = 3.14159265358979323846f;

__device__ __forceinline__ half2v pack_weights(float a, float b) {
    return __builtin_bit_cast(half2v, __builtin_amdgcn_cvt_pkrtz(a, b));
}

// ---------------------------------------------------------------------------
// Stage 1: ramp filter, truncated symmetric convolution, angle-quad blocks.
//   xf[d] = 0.5*r[d] + sum_{t odd,<=63} h(t)*(r[d-t]+r[d+t]), h(t)=-2/(pi t)^2
// Block = (bc, 4 consecutive angles); 16B float4 input loads over the
// contiguous angle axis. bc=0 blocks also emit the GLOBAL trig table
// trigg[a] = (cos*255.5, sin*255.5) used by stage 2 (removes the per-angle
// LDS read from the backprojection inner loop — model v4's serial cost).
// Grid: 90 blocks x 512 threads.
// ---------------------------------------------------------------------------
__global__ __launch_bounds__(512) void ramp_filter_kernel(
    const float* __restrict__ x, unsigned* __restrict__ xfh,
    float2* __restrict__ trigg) {
    __shared__ float rp[4][640];         // per row: [0,64)=0, [64,576), [576,640)=0
    __shared__ float xf[4][D_DET + 1];

    const int blk = blockIdx.x;
    const int bc  = blk / 45;            // 0..1
    const int a0  = (blk % 45) * 4;
    const int d   = threadIdx.x;

    if (bc == 0 && d < 4) {              // emit global trig table (45 blocks x 4)
        float th = (float)(a0 + d) * (kPI / 180.0f);
        float s, c;
        sincosf(th, &s, &c);
        trigg[a0 + d] = make_float2(c * 255.5f, s * 255.5f);
    }

    // Stage 4 rows; input contiguous over angles -> one float4 per lane.
    float4 q = *(const float4*)(x + (bc * D_DET + d) * N_ANG + a0);
    rp[0][64 + d] = q.x;
    rp[1][64 + d] = q.y;
    rp[2][64 + d] = q.z;
    rp[3][64 + d] = q.w;
    if (d < 64) {
        #pragma unroll
        for (int r = 0; r < 4; ++r) { rp[r][d] = 0.0f; rp[r][576 + d] = 0.0f; }
    }
    if (d < 4) xf[d][D_DET] = 0.0f;
    __syncthreads();

    constexpr float PI_ = 3.14159265358979323846f;
    #pragma unroll
    for (int r = 0; r < 4; ++r) {
        const float* rm = &rp[r][64 + d];
        float acc = 0.5f * rm[0];
        #pragma unroll
        for (int k = 0; k < (T_MAX + 1) / 2; ++k) {
            const int   t = 2 * k + 1;
            const float h = -2.0f / (PI_ * PI_ * (float)(t * t));   // literal
            acc = fmaf(rm[-t] + rm[t], h, acc);
        }
        xf[r][d] = acc;
    }
    __syncthreads();

    #pragma unroll
    for (int r = 0; r < 4; ++r) {
        const unsigned lo = __half_as_ushort(__float2half_rn(xf[r][d]));
        const unsigned hi = __half_as_ushort(__float2half_rn(xf[r][d + 1]));
        xfh[((a0 + r) * D_DET + d) * 2 + bc] = (hi << 16) | lo;
    }
}

// ---------------------------------------------------------------------------
// Stage 2: backprojection, ZERO LDS in the inner loop.
// trigg[a] is a loop-uniform global read -> scalar-cache / uniform 8B
// (vs R1-R13: a per-angle LDS ds_read_b64, ~8 cyc x 180 x 2880 visits/CU
// ~ 9.6 us of serialized LDS-pipe time -- model v4's removable component).
// Wave = compact 8x8 pixel patch; thread = 1 pixel, both images:
// one 8B uint2 gather + cvt_pkrtz + 2 fdot2 per angle.
// Grid: 1024 blocks x 256 threads, no shared memory.
// ---------------------------------------------------------------------------
__global__ __launch_bounds__(256) void backproj_kernel(
    const uint2* __restrict__ xfh, const float2* __restrict__ trigg,
    float* __restrict__ out) {
    const int tid  = threadIdx.x;
    const int bi   = blockIdx.x >> 5;    // 32 i-tiles of 16
    const int bj   = blockIdx.x & 31;    // 32 j-tiles of 16
    const int wave = tid >> 6;
    const int lane = tid & 63;
    const int i = (bi << 4) + ((wave >> 1) << 3) + (lane >> 3);
    const int j = (bj << 4) + ((wave & 1) << 3) + (lane & 7);

    const float xP = (float)j * (2.0f / 511.0f) - 1.0f;
    const float yP = (float)i * (2.0f / 511.0f) - 1.0f;
    const float m  = xP * xP + yP * yP;
    const int  p   = i * S_IMG + j;

    if (!__any(m <= 1.0f)) {             // whole 8x8 patch outside circle
        out[p]        = 0.0f;
        out[NPIX + p] = 0.0f;
        return;
    }

    float a0 = 0.0f, a1 = 0.0f;
    #pragma unroll 4
    for (int a = 0; a < N_ANG; ++a) {
        float2 t  = trigg[a];            // uniform index -> scalar pipe
        float pc  = fminf(fmaxf(fmaf(xP, t.x, fmaf(yP, -t.y, 255.5f)), 0.0f), 511.0f);
        float fi  = floorf(pc);
        float w   = pc - fi;
        half2v hw = pack_weights(1.0f - w, w);
        uint2  g  = xfh[(a << 9) + (int)fi];
        a0 = __builtin_amdgcn_fdot2(hw, __builtin_bit_cast(half2v, g.x), a0, false);
        a1 = __builtin_amdgcn_fdot2(hw, __builtin_bit_cast(half2v, g.y), a1, false);
    }

    const float msk = (m <= 1.0f) ? (kPI / (2.0f * (float)N_ANG)) : 0.0f;
    out[p]        = a0 * msk;
    out[NPIX + p] = a1 * msk;
}

// ---------------------------------------------------------------------------
extern "C" void kernel_launch(void* const* d_in, const int* in_sizes, int n_in,
                              void* d_out, int out_size, void* d_ws, size_t ws_size,
                              hipStream_t stream) {
    const float* x    = (const float*)d_in[0];
    float*       out  = (float*)d_out;
    unsigned*    xfh  = (unsigned*)d_ws;                      // 737,280 B
    float2*      trg  = (float2*)((char*)d_ws + 737280);      // 1,440 B

    ramp_filter_kernel<<<90, 512, 0, stream>>>(x, xfh, trg);
    backproj_kernel<<<1024, 256, 0, stream>>>((const uint2*)xfh, trg, out);
}